// Round 3
// baseline (93.228 us; speedup 1.0000x reference)
//
#include <hip/hip_runtime.h>

// out = atoms_x - segment_mean(atoms_x, graph_batch)[graph_batch]
// graph_batch SORTED. Fused single pass, fully COALESCED (interleaved
// assignment: iter j, thread t -> atom cs + j*TPB + t). Segment sums via
// wave-level distinct-id reduction (sorted => ~2.6 runs / 64-lane window),
// flushed to per-block LDS slots. Halo scans complete edge molecules.

static constexpr int TPB   = 256;
static constexpr int CPT   = 4;            // atoms per thread
static constexpr int CHUNK = TPB * CPT;    // 1024 atoms per block
static constexpr int SLOTS = 256;          // max id-span per chunk (exp ~27)

__global__ __launch_bounds__(TPB) void fused_center_kernel(
    const float* __restrict__ x, const int* __restrict__ gb,
    float* __restrict__ out, int n) {
  __shared__ float sums[SLOTS * 4];  // {sx, sy, sz, cnt} per slot

  const long long cs = (long long)blockIdx.x * CHUNK;
  const long long ce = (cs + CHUNK < (long long)n) ? cs + CHUNK : (long long)n;
  const int fid = gb[cs];
  const int lid = gb[ce - 1];
  const int span = lid - fid + 1;

  if (span > SLOTS) {
    // Pathological id-sparsity (huge empty-molecule gaps); block-uniform
    // branch, returns before any __syncthreads. Correct, never hot.
    if (threadIdx.x == 0) {
      long long i = cs;
      while (i < ce) {
        int id = gb[i];
        long long rs = i; while (rs > 0 && gb[rs - 1] == id) --rs;
        long long re = i; while (re < n && gb[re] == id) ++re;
        float sx = 0.f, sy = 0.f, sz = 0.f;
        for (long long k = rs; k < re; ++k) {
          sx += x[k * 3 + 0]; sy += x[k * 3 + 1]; sz += x[k * 3 + 2];
        }
        float inv = 1.f / (float)(re - rs);
        float mx = sx * inv, my = sy * inv, mz = sz * inv;
        long long we = (re < ce) ? re : ce;
        for (long long k = i; k < we; ++k) {
          out[k * 3 + 0] = x[k * 3 + 0] - mx;
          out[k * 3 + 1] = x[k * 3 + 1] - my;
          out[k * 3 + 2] = x[k * 3 + 2] - mz;
        }
        i = we;
      }
    }
    return;
  }

  for (int i = threadIdx.x; i < span * 4; i += TPB) sums[i] = 0.f;
  __syncthreads();

  // ---- coalesced loads (12 B/lane, dense lines), interleaved ----
  float vx[CPT], vy[CPT], vz[CPT];
  int ids[CPT];
#pragma unroll
  for (int j = 0; j < CPT; ++j) {
    long long a = cs + (long long)j * TPB + threadIdx.x;
    if (a < ce) {
      const float* p = x + a * 3;
      vx[j] = p[0]; vy[j] = p[1]; vz[j] = p[2];
      ids[j] = gb[a];
    } else {
      vx[j] = 0.f; vy[j] = 0.f; vz[j] = 0.f;
      ids[j] = -2;  // sentinel: never flushed
    }
  }

  // ---- wave-level segmented reduce: loop over distinct ids in window ----
  const int lane = threadIdx.x & 63;
#pragma unroll
  for (int j = 0; j < CPT; ++j) {
    unsigned long long remaining = __ballot(true);
    while (remaining) {
      int ldr = __ffsll(remaining) - 1;
      int lead_id = __shfl(ids[j], ldr);
      bool in = (ids[j] == lead_id);
      unsigned long long m = __ballot(in);
      float rx = in ? vx[j] : 0.f;
      float ry = in ? vy[j] : 0.f;
      float rz = in ? vz[j] : 0.f;
#pragma unroll
      for (int d = 1; d < 64; d <<= 1) {
        rx += __shfl_xor(rx, d);
        ry += __shfl_xor(ry, d);
        rz += __shfl_xor(rz, d);
      }
      if (lane == ldr && lead_id >= 0) {
        int s = (lead_id - fid) * 4;
        atomicAdd(&sums[s + 0], rx);
        atomicAdd(&sums[s + 1], ry);
        atomicAdd(&sums[s + 2], rz);
        atomicAdd(&sums[s + 3], (float)__popcll(m));
      }
      remaining &= ~m;
    }
  }

  // ---- halos: complete the edge molecules (redundant ownership) ----
  if (cs > 0 && threadIdx.x < 64) {
    float hx = 0.f, hy = 0.f, hz = 0.f, hc = 0.f;
    long long i = cs - 1 - (long long)threadIdx.x;
    while (i >= 0 && gb[i] == fid) {
      hx += x[i * 3 + 0]; hy += x[i * 3 + 1]; hz += x[i * 3 + 2]; hc += 1.f;
      i -= 64;
    }
    if (hc > 0.f) {
      atomicAdd(&sums[0], hx); atomicAdd(&sums[1], hy);
      atomicAdd(&sums[2], hz); atomicAdd(&sums[3], hc);
    }
  }
  if (ce < (long long)n && threadIdx.x >= 64 && threadIdx.x < 128) {
    int hl = threadIdx.x - 64;
    float hx = 0.f, hy = 0.f, hz = 0.f, hc = 0.f;
    long long i = ce + hl;
    while (i < (long long)n && gb[i] == lid) {
      hx += x[i * 3 + 0]; hy += x[i * 3 + 1]; hz += x[i * 3 + 2]; hc += 1.f;
      i += 64;
    }
    if (hc > 0.f) {
      int s = (lid - fid) * 4;
      atomicAdd(&sums[s + 0], hx); atomicAdd(&sums[s + 1], hy);
      atomicAdd(&sums[s + 2], hz); atomicAdd(&sums[s + 3], hc);
    }
  }
  __syncthreads();

  // ---- sums -> means ----
  for (int s = threadIdx.x; s < span; s += TPB) {
    float c = sums[s * 4 + 3];
    if (c > 0.f) {
      float inv = 1.f / c;
      sums[s * 4 + 0] *= inv; sums[s * 4 + 1] *= inv; sums[s * 4 + 2] *= inv;
    }
  }
  __syncthreads();

  // ---- subtract + coalesced store (12 B/lane, dense lines) ----
#pragma unroll
  for (int j = 0; j < CPT; ++j) {
    long long a = cs + (long long)j * TPB + threadIdx.x;
    if (a < ce) {
      int s = (ids[j] - fid) * 4;
      float* q = out + a * 3;
      q[0] = vx[j] - sums[s + 0];
      q[1] = vy[j] - sums[s + 1];
      q[2] = vz[j] - sums[s + 2];
    }
  }
}

extern "C" void kernel_launch(void* const* d_in, const int* in_sizes, int n_in,
                              void* d_out, int out_size, void* d_ws, size_t ws_size,
                              hipStream_t stream) {
  const float* x = (const float*)d_in[0];
  const int* gb = (const int*)d_in[1];
  float* out = (float*)d_out;
  const int n = in_sizes[0] / 3;  // atoms

  int blocks = (int)(((long long)n + CHUNK - 1) / CHUNK);
  fused_center_kernel<<<blocks, TPB, 0, stream>>>(x, gb, out, n);
}

// Round 4
// 63.641 us; speedup vs baseline: 1.4649x; 1.4649x over previous
//
#include <hip/hip_runtime.h>

// out = atoms_x - segment_mean(atoms_x, graph_batch)[graph_batch]
// graph_batch SORTED. Fused single pass. Round-2 structure (chunked float4
// loads + per-thread run accumulation, LDS slot flush, halo completion) with
// SLOTS 2048->256 (LDS 32KB->4KB) to lift occupancy 5->8 blocks/CU, and
// global loads hoisted above the LDS-zero barrier to hide latency.

static constexpr int TPB   = 256;
static constexpr int CPT   = 8;            // atoms per thread
static constexpr int CHUNK = TPB * CPT;    // 2048 atoms per block
static constexpr int SLOTS = 256;          // max id-span per chunk (exp ~52)

__global__ __launch_bounds__(TPB) void fused_center_kernel(
    const float* __restrict__ x, const int* __restrict__ gb,
    float* __restrict__ out, int n) {
  __shared__ float sums[SLOTS * 4];  // {sx, sy, sz, cnt} per slot

  const long long cs = (long long)blockIdx.x * CHUNK;
  const long long ce = (cs + CHUNK < (long long)n) ? cs + CHUNK : (long long)n;
  const int fid = gb[cs];
  const int lid = gb[ce - 1];
  const int span = lid - fid + 1;

  if (span > SLOTS) {
    // Pathological id-sparsity (huge empty-molecule gaps); block-uniform
    // branch, returns before any __syncthreads. Correct, never hot.
    if (threadIdx.x == 0) {
      long long i = cs;
      while (i < ce) {
        int id = gb[i];
        long long rs = i; while (rs > 0 && gb[rs - 1] == id) --rs;
        long long re = i; while (re < n && gb[re] == id) ++re;
        float sx = 0.f, sy = 0.f, sz = 0.f;
        for (long long k = rs; k < re; ++k) {
          sx += x[k * 3 + 0]; sy += x[k * 3 + 1]; sz += x[k * 3 + 2];
        }
        float inv = 1.f / (float)(re - rs);
        float mx = sx * inv, my = sy * inv, mz = sz * inv;
        long long we = (re < ce) ? re : ce;
        for (long long k = i; k < we; ++k) {
          out[k * 3 + 0] = x[k * 3 + 0] - mx;
          out[k * 3 + 1] = x[k * 3 + 1] - my;
          out[k * 3 + 2] = x[k * 3 + 2] - mz;
        }
        i = we;
      }
    }
    return;
  }

  const long long base = cs + (long long)threadIdx.x * CPT;
  const bool full = (base + CPT <= ce);

  // ---- issue global loads BEFORE the LDS-zero barrier (hide latency) ----
  float f[CPT * 3];
  int ids[CPT];
  if (full) {
    const float4* xv = reinterpret_cast<const float4*>(x + base * 3);
    float4 v0 = xv[0], v1 = xv[1], v2 = xv[2],
           v3 = xv[3], v4 = xv[4], v5 = xv[5];
    const int4* gv = reinterpret_cast<const int4*>(gb + base);
    int4 g0 = gv[0], g1 = gv[1];
    f[0]=v0.x; f[1]=v0.y; f[2]=v0.z; f[3]=v0.w;
    f[4]=v1.x; f[5]=v1.y; f[6]=v1.z; f[7]=v1.w;
    f[8]=v2.x; f[9]=v2.y; f[10]=v2.z; f[11]=v2.w;
    f[12]=v3.x; f[13]=v3.y; f[14]=v3.z; f[15]=v3.w;
    f[16]=v4.x; f[17]=v4.y; f[18]=v4.z; f[19]=v4.w;
    f[20]=v5.x; f[21]=v5.y; f[22]=v5.z; f[23]=v5.w;
    ids[0]=g0.x; ids[1]=g0.y; ids[2]=g0.z; ids[3]=g0.w;
    ids[4]=g1.x; ids[5]=g1.y; ids[6]=g1.z; ids[7]=g1.w;
  }

  // zero only the slots this chunk can touch
  for (int i = threadIdx.x; i < span * 4; i += TPB) sums[i] = 0.f;
  __syncthreads();

  if (full) {
    // ---- per-thread run accumulation, flush at id boundaries ----
    int cur = ids[0];
    float sx = 0.f, sy = 0.f, sz = 0.f, sc = 0.f;
#pragma unroll
    for (int j = 0; j < CPT; ++j) {
      if (ids[j] != cur) {
        int s = (cur - fid) * 4;
        atomicAdd(&sums[s + 0], sx); atomicAdd(&sums[s + 1], sy);
        atomicAdd(&sums[s + 2], sz); atomicAdd(&sums[s + 3], sc);
        cur = ids[j]; sx = sy = sz = sc = 0.f;
      }
      sx += f[j * 3 + 0]; sy += f[j * 3 + 1]; sz += f[j * 3 + 2]; sc += 1.f;
    }
    {
      int s = (cur - fid) * 4;
      atomicAdd(&sums[s + 0], sx); atomicAdd(&sums[s + 1], sy);
      atomicAdd(&sums[s + 2], sz); atomicAdd(&sums[s + 3], sc);
    }
  } else if (base < ce) {
    // tail atoms (last block only)
    for (long long i = base; i < ce; ++i) {
      int s = (gb[i] - fid) * 4;
      atomicAdd(&sums[s + 0], x[i * 3 + 0]);
      atomicAdd(&sums[s + 1], x[i * 3 + 1]);
      atomicAdd(&sums[s + 2], x[i * 3 + 2]);
      atomicAdd(&sums[s + 3], 1.f);
    }
  }

  // ---- halos: complete the edge molecules (redundant ownership) ----
  if (cs > 0 && threadIdx.x < 64) {
    float hx = 0.f, hy = 0.f, hz = 0.f, hc = 0.f;
    long long i = cs - 1 - (long long)threadIdx.x;
    while (i >= 0 && gb[i] == fid) {
      hx += x[i * 3 + 0]; hy += x[i * 3 + 1]; hz += x[i * 3 + 2]; hc += 1.f;
      i -= 64;
    }
    if (hc > 0.f) {
      atomicAdd(&sums[0], hx); atomicAdd(&sums[1], hy);
      atomicAdd(&sums[2], hz); atomicAdd(&sums[3], hc);
    }
  }
  if (ce < (long long)n && threadIdx.x >= 64 && threadIdx.x < 128) {
    int hl = threadIdx.x - 64;
    float hx = 0.f, hy = 0.f, hz = 0.f, hc = 0.f;
    long long i = ce + hl;
    while (i < (long long)n && gb[i] == lid) {
      hx += x[i * 3 + 0]; hy += x[i * 3 + 1]; hz += x[i * 3 + 2]; hc += 1.f;
      i += 64;
    }
    if (hc > 0.f) {
      int s = (lid - fid) * 4;
      atomicAdd(&sums[s + 0], hx); atomicAdd(&sums[s + 1], hy);
      atomicAdd(&sums[s + 2], hz); atomicAdd(&sums[s + 3], hc);
    }
  }
  __syncthreads();

  // ---- sums -> means (in LDS) ----
  for (int s = threadIdx.x; s < span; s += TPB) {
    float c = sums[s * 4 + 3];
    if (c > 0.f) {
      float inv = 1.f / c;
      sums[s * 4 + 0] *= inv; sums[s * 4 + 1] *= inv; sums[s * 4 + 2] *= inv;
    }
  }
  __syncthreads();

  // ---- subtract + write ----
  if (full) {
    float o[CPT * 3];
#pragma unroll
    for (int j = 0; j < CPT; ++j) {
      int s = (ids[j] - fid) * 4;
      o[j * 3 + 0] = f[j * 3 + 0] - sums[s + 0];
      o[j * 3 + 1] = f[j * 3 + 1] - sums[s + 1];
      o[j * 3 + 2] = f[j * 3 + 2] - sums[s + 2];
    }
    float4* ov = reinterpret_cast<float4*>(out + base * 3);
#pragma unroll
    for (int j = 0; j < CPT * 3 / 4; ++j)
      ov[j] = make_float4(o[j * 4 + 0], o[j * 4 + 1], o[j * 4 + 2], o[j * 4 + 3]);
  } else if (base < ce) {
    for (long long i = base; i < ce; ++i) {
      int s = (gb[i] - fid) * 4;
      out[i * 3 + 0] = x[i * 3 + 0] - sums[s + 0];
      out[i * 3 + 1] = x[i * 3 + 1] - sums[s + 1];
      out[i * 3 + 2] = x[i * 3 + 2] - sums[s + 2];
    }
  }
}

extern "C" void kernel_launch(void* const* d_in, const int* in_sizes, int n_in,
                              void* d_out, int out_size, void* d_ws, size_t ws_size,
                              hipStream_t stream) {
  const float* x = (const float*)d_in[0];
  const int* gb = (const int*)d_in[1];
  float* out = (float*)d_out;
  const int n = in_sizes[0] / 3;  // atoms

  int blocks = (int)(((long long)n + CHUNK - 1) / CHUNK);
  fused_center_kernel<<<blocks, TPB, 0, stream>>>(x, gb, out, n);
}